// Round 9
// baseline (205.042 us; speedup 1.0000x reference)
//
#include <hip/hip_runtime.h>

// Causal MHA forward, B=2 T=2048 C=1024 H=16 hs=64, fp32 in/out, bf16 MFMA internally.
// R9: flash = 2-wave blocks x 32q/wave (K/V frag reads amortized over 2 q-strips,
// 1440-block grid kept); prep kernels merged; vT folded into qkv epilogue (LDS transpose,
// coalesced V writes). XCD-grouped flash jobs, rotation-swizzled LDS throughout.

typedef unsigned short u16;
typedef unsigned int u32;
typedef __bf16 bf16x8 __attribute__((ext_vector_type(8)));
typedef float f32x4 __attribute__((ext_vector_type(4)));
typedef u32 u32x4 __attribute__((ext_vector_type(4)));
typedef u16 u16x4 __attribute__((ext_vector_type(4)));

__device__ __forceinline__ u16 f2bf(float f) {
  u32 u = __float_as_uint(f);
  u32 r = u + 0x7FFFu + ((u >> 16) & 1u);  // RNE, finite inputs only
  return (u16)(r >> 16);
}

__device__ __forceinline__ bf16x8 ld_bf8(const u16* p) {
  union { u32x4 u; bf16x8 b; } x;
  x.u = *(const u32x4*)p;
  return x.b;
}

__device__ __forceinline__ void gld_lds16(const u16* g, u16* l) {
  __builtin_amdgcn_global_load_lds(
      (const __attribute__((address_space(1))) u32*)g,
      (__attribute__((address_space(3))) u32*)l, 16, 0, 0);
}

// ---- merged prep: fp32->bf16 x-convert + both weight transpose-converts ----
__device__ __forceinline__ void convT_body(const float* __restrict__ src,
                                           u16* __restrict__ dst, int R, int Cc,
                                           int r0, int c0, float* ls /*64x65*/) {
  int t = threadIdx.x;
  for (int u = t; u < 1024; u += 256) {
    int r = u >> 4, cs = (u & 15) << 2;
    float4 v = *(const float4*)&src[(size_t)(r0 + r) * Cc + (c0 + cs)];
    ls[r * 65 + cs] = v.x; ls[r * 65 + cs + 1] = v.y;
    ls[r * 65 + cs + 2] = v.z; ls[r * 65 + cs + 3] = v.w;
  }
  __syncthreads();
  for (int u = t; u < 1024; u += 256) {
    int n = u >> 4, ks = (u & 15) << 2;
    u16x4 o;
    o.x = f2bf(ls[ks * 65 + n]); o.y = f2bf(ls[(ks + 1) * 65 + n]);
    o.z = f2bf(ls[(ks + 2) * 65 + n]); o.w = f2bf(ls[(ks + 3) * 65 + n]);
    *(u16x4*)&dst[(size_t)(c0 + n) * R + (r0 + ks)] = o;
  }
}

__global__ __launch_bounds__(256) void prep_kernel(
    const float* __restrict__ x, const float* __restrict__ Wkqv,
    const float* __restrict__ Wproj, u16* __restrict__ xb,
    u16* __restrict__ wkqvT, u16* __restrict__ wprojT) {
  __shared__ float ls[64 * 65];
  int bx = blockIdx.x;
  if (bx < 2048) {  // x -> bf16, 8 elems/thread
    int idx = bx * 256 + threadIdx.x;
    const float4* s4 = (const float4*)x;
    float4 a = s4[2 * idx], b = s4[2 * idx + 1];
    union { u16 h[8]; u32x4 v; } pk;
    pk.h[0] = f2bf(a.x); pk.h[1] = f2bf(a.y); pk.h[2] = f2bf(a.z); pk.h[3] = f2bf(a.w);
    pk.h[4] = f2bf(b.x); pk.h[5] = f2bf(b.y); pk.h[6] = f2bf(b.z); pk.h[7] = f2bf(b.w);
    *(u32x4*)&xb[(size_t)idx * 8] = pk.v;
  } else if (bx < 2816) {  // W_kqv^T (1024x3072 -> 3072x1024)
    int idx = bx - 2048;
    convT_body(Wkqv, wkqvT, 1024, 3072, (idx & 15) * 64, (idx >> 4) * 64, ls);
  } else {                 // W_proj^T (1024x1024 -> 1024x1024)
    int idx = bx - 2816;
    convT_body(Wproj, wprojT, 1024, 1024, (idx & 15) * 64, (idx >> 4) * 64, ls);
  }
}

// ---- QKV GEMM: 128x128 tile, 4 waves x (64x64), BK=32, K=1024 ----
// Q/K blocks: scattered u16 epilogue. V blocks (n0>=2048): in-LDS transpose,
// coalesced dwordx4 writes straight into Vt[bh][d][t] (vT kernel eliminated).
__global__ __launch_bounds__(256) void qkv_gemm_kernel(
    const u16* __restrict__ A, const u16* __restrict__ Bt,
    u16* __restrict__ Qh, u16* __restrict__ Kh, u16* __restrict__ Vt, float qscale) {
  constexpr int K = 1024;
  __shared__ __align__(16) u16 smem[8704];  // As+Bs (16KB) in K-loop; 64x136 transpose after
  u16* As = smem;
  u16* Bs = smem + 4096;
  int t = threadIdx.x;
  int wave = t >> 6, lane = t & 63, quad = lane >> 4, l16 = lane & 15;
  int wm = (wave >> 1) << 6, wn = (wave & 1) << 6;
  int m0 = blockIdx.x * 128, n0 = blockIdx.y * 128;
  f32x4 acc[4][4] = {};
  int u0 = t, u1 = t + 256;
  int ra0 = u0 >> 2, ca0 = ((u0 & 3) ^ ((u0 >> 3) & 3)) << 3;
  int ra1 = u1 >> 2, ca1 = ((u1 & 3) ^ ((u1 >> 3) & 3)) << 3;
  int swq = (quad ^ ((l16 >> 1) & 3)) << 3;
  for (int k0 = 0; k0 < K; k0 += 32) {
    gld_lds16(&A[(size_t)(m0 + ra0) * K + k0 + ca0], &As[u0 * 8]);
    gld_lds16(&A[(size_t)(m0 + ra1) * K + k0 + ca1], &As[u1 * 8]);
    gld_lds16(&Bt[(size_t)(n0 + ra0) * K + k0 + ca0], &Bs[u0 * 8]);
    gld_lds16(&Bt[(size_t)(n0 + ra1) * K + k0 + ca1], &Bs[u1 * 8]);
    __syncthreads();
    bf16x8 af[4], bfr[4];
    for (int r = 0; r < 4; ++r) af[r] = ld_bf8(&As[(wm + r * 16 + l16) * 32 + swq]);
    for (int c = 0; c < 4; ++c) bfr[c] = ld_bf8(&Bs[(wn + c * 16 + l16) * 32 + swq]);
    for (int r = 0; r < 4; ++r)
      for (int c = 0; c < 4; ++c)
        acc[r][c] = __builtin_amdgcn_mfma_f32_16x16x32_bf16(af[r], bfr[c], acc[r][c], 0, 0, 0);
    __syncthreads();
  }
  if (n0 < 2048) {  // Q or K scatter ([bh][t][d], 2B stores)
    for (int r = 0; r < 4; ++r) {
      int rowbase = m0 + wm + r * 16 + quad * 4;
      for (int c = 0; c < 4; ++c) {
        int col = n0 + wn + c * 16 + l16;
        int seg = col >> 10;
        int cc = col & 1023;
        int h = cc >> 6, d = cc & 63;
        for (int i = 0; i < 4; ++i) {
          int row = rowbase + i;
          int b = row >> 11, tt = row & 2047;
          size_t off = (((size_t)(b * 16 + h)) * 2048 + tt) * 64 + d;
          float v = acc[r][c][i];
          if (seg == 0) Qh[off] = f2bf(v * qscale);
          else          Kh[off] = f2bf(v);
        }
      }
    }
  } else {  // V: transpose 128 rows x 128 cols (2 heads) through LDS, coalesced Vt writes
    int h0 = (n0 - 2048) >> 6;
    int b = m0 >> 11, tt0 = m0 & 2047;
    for (int p = 0; p < 2; ++p) {  // pass p handles cols [p*64, p*64+64) = head h0+p
      __syncthreads();
      if (wn == p * 64) {  // the 2 waves owning this col-half write their acc quadrant
        for (int r = 0; r < 4; ++r) {
          int row = wm + r * 16 + quad * 4;  // block-local row (4 consecutive via i)
          for (int c = 0; c < 4; ++c) {
            int col = c * 16 + l16;          // 0..63 within pass
            union { u16 hh[4]; u16x4 v; } pk;
            for (int i = 0; i < 4; ++i) pk.hh[i] = f2bf(acc[r][c][i]);
            *(u16x4*)&smem[col * 136 + row] = pk.v;  // ls[col][row], stride 136
          }
        }
      }
      __syncthreads();
      int bh = b * 16 + h0 + p;
      for (int w = t; w < 1024; w += 256) {  // 64 cols x 16 chunks of 8 t-values
        int col = w >> 4, ch = w & 15;
        u32x4 v = *(u32x4*)&smem[col * 136 + ch * 8];
        *(u32x4*)&Vt[((size_t)bh * 64 + col) * 2048 + tt0 + ch * 8] = v;
      }
    }
  }
}

// ---- proj GEMM: 128x128 tile, 8 waves (2x4 grid, wave tile 64x32), grid (32,8) ----
__global__ __launch_bounds__(512) void proj_gemm_kernel(
    const u16* __restrict__ A, const u16* __restrict__ Bt,
    float* __restrict__ out, const float* __restrict__ bias) {
  constexpr int K = 1024;
  __shared__ __align__(16) u16 As[128 * 32];
  __shared__ __align__(16) u16 Bs[128 * 32];
  int t = threadIdx.x;
  int wave = t >> 6, lane = t & 63, quad = lane >> 4, l16 = lane & 15;
  int wm = (wave >> 2) << 6, wn = (wave & 3) << 5;
  int m0 = blockIdx.x * 128, n0 = blockIdx.y * 128;
  f32x4 acc[4][2] = {};
  int u0 = t;
  int ra0 = u0 >> 2, ca0 = ((u0 & 3) ^ ((u0 >> 3) & 3)) << 3;
  int swq = (quad ^ ((l16 >> 1) & 3)) << 3;
  for (int k0 = 0; k0 < K; k0 += 32) {
    gld_lds16(&A[(size_t)(m0 + ra0) * K + k0 + ca0], &As[u0 * 8]);
    gld_lds16(&Bt[(size_t)(n0 + ra0) * K + k0 + ca0], &Bs[u0 * 8]);
    __syncthreads();
    bf16x8 af[4], bfr[2];
    for (int r = 0; r < 4; ++r) af[r] = ld_bf8(&As[(wm + r * 16 + l16) * 32 + swq]);
    for (int c = 0; c < 2; ++c) bfr[c] = ld_bf8(&Bs[(wn + c * 16 + l16) * 32 + swq]);
    for (int r = 0; r < 4; ++r)
      for (int c = 0; c < 2; ++c)
        acc[r][c] = __builtin_amdgcn_mfma_f32_16x16x32_bf16(af[r], bfr[c], acc[r][c], 0, 0, 0);
    __syncthreads();
  }
  for (int r = 0; r < 4; ++r) {
    int rowbase = m0 + wm + r * 16 + quad * 4;
    for (int c = 0; c < 2; ++c) {
      int col = n0 + wn + c * 16 + l16;
      float bv = bias[col];
      for (int i = 0; i < 4; ++i)
        out[(size_t)(rowbase + i) * 1024 + col] = acc[r][c][i] + bv;
    }
  }
}

// ---- flash attention: 2 waves x 32 q-rows (BQ=64), S^T form, static-max exp2 softmax ----
// K/V frag reads shared across each wave's 2 q-strips. Rotation-swizzled stride-64 LDS.
// 1440-block XCD-grouped grid (same-bh jobs share an XCD via id%8).
__global__ __launch_bounds__(128, 3) void flash_kernel(
    const u16* __restrict__ Qh, const u16* __restrict__ Kh, const u16* __restrict__ Vt,
    u16* __restrict__ yb, float* __restrict__ Opart) {
  __shared__ __align__(16) u16 Ks[64 * 64];
  __shared__ __align__(16) u16 Vs[64 * 64];
  __shared__ __align__(16) u16 Ps[64 * 64];
  int t = threadIdx.x, wave = t >> 6, lane = t & 63, quad = lane >> 4, l16 = lane & 15;
  int id = blockIdx.x;                 // 0..1439
  int g = id / 360, r = id % 360;
  int bh = g * 8 + (r & 7);            // same-bh jobs share an XCD
  int jx = r >> 3;                     // 0..44, longest first
  int qtile, kvs, kve, sidx = 0, half = 0;
  bool partial;
  if (jx < 19) {                       // full jobs: qtile 18..0
    qtile = 18 - jx; kvs = 0; kve = qtile + 1; partial = false;
  } else {                             // split jobs: qtile 31..19, 2 halves (<=16 iters)
    sidx = (jx - 19) >> 1; half = (jx - 19) & 1;
    qtile = 31 - sidx;
    int nkv = qtile + 1, mid = nkv >> 1;
    kvs = half ? mid : 0; kve = half ? nkv : mid; partial = true;
  }
  int q0 = qtile << 6;
  const u16* Qb = Qh + (size_t)bh * 2048 * 64;
  const u16* Kb = Kh + (size_t)bh * 2048 * 64;
  const u16* Vb = Vt + (size_t)bh * 64 * 2048;
  bf16x8 qa[2][2];  // 2 q-strips x 2 k-halves (B-operand)
  for (int s = 0; s < 2; ++s) {
    int qrow = q0 + wave * 32 + s * 16 + l16;
    qa[s][0] = ld_bf8(&Qb[(size_t)qrow * 64 + quad * 8]);
    qa[s][1] = ld_bf8(&Qb[(size_t)qrow * 64 + 32 + quad * 8]);
  }
  f32x4 oacc[2][4] = {};
  float lsum[2] = {0.f, 0.f};
  for (int j = kvs; j < kve; ++j) {
    int kv0 = j << 6;
    __syncthreads();  // previous tile fully consumed
    for (int k = 0; k < 4; ++k) {  // 512 16B-units per tile, 8 gld/lane (4 K + 4 V)
      int u = wave * 256 + k * 64 + lane;
      int row = u >> 3, cb = ((u & 7) - row) & 7;
      gld_lds16(&Kb[(size_t)(kv0 + row) * 64 + cb * 8], &Ks[u * 8]);
      gld_lds16(&Vb[(size_t)row * 2048 + kv0 + cb * 8], &Vs[u * 8]);
    }
    __syncthreads();  // vmcnt drain -> tiles ready
    bool maskit = (j == qtile);
    for (int c = 0; c < 4; ++c) {
      int krow = c * 16 + l16;
      bf16x8 kb0 = ld_bf8(&Ks[krow * 64 + ((quad + krow) & 7) * 8]);
      bf16x8 kb1 = ld_bf8(&Ks[krow * 64 + ((quad + 4 + krow) & 7) * 8]);
      for (int s = 0; s < 2; ++s) {
        f32x4 z = {0.f, 0.f, 0.f, 0.f};
        z = __builtin_amdgcn_mfma_f32_16x16x32_bf16(kb0, qa[s][0], z, 0, 0, 0);
        z = __builtin_amdgcn_mfma_f32_16x16x32_bf16(kb1, qa[s][1], z, 0, 0, 0);
        int prow = wave * 32 + s * 16 + l16;
        union { u16 hh[4]; u16x4 v; } pk;
        if (maskit) {
          int qg = q0 + prow;
          for (int i = 0; i < 4; ++i) {
            float p = __builtin_amdgcn_exp2f(z[i]);
            if (kv0 + c * 16 + quad * 4 + i > qg) p = 0.f;
            lsum[s] += p;
            pk.hh[i] = f2bf(p);
          }
        } else {
          for (int i = 0; i < 4; ++i) {
            float p = __builtin_amdgcn_exp2f(z[i]);
            lsum[s] += p;
            pk.hh[i] = f2bf(p);
          }
        }
        *(u16x4*)&Ps[prow * 64 + ((2 * c + (quad >> 1) + prow) & 7) * 8 + (quad & 1) * 4] =
            pk.v;
      }
    }
    bf16x8 pa[2][2];  // wave-private rows, no barrier needed
    for (int s = 0; s < 2; ++s) {
      int prow = wave * 32 + s * 16 + l16;
      pa[s][0] = ld_bf8(&Ps[prow * 64 + ((quad + prow) & 7) * 8]);
      pa[s][1] = ld_bf8(&Ps[prow * 64 + ((quad + 4 + prow) & 7) * 8]);
    }
    for (int dt = 0; dt < 4; ++dt) {
      int vrow = dt * 16 + l16;
      bf16x8 vb0 = ld_bf8(&Vs[vrow * 64 + ((quad + vrow) & 7) * 8]);
      bf16x8 vb1 = ld_bf8(&Vs[vrow * 64 + ((quad + 4 + vrow) & 7) * 8]);
      for (int s = 0; s < 2; ++s) {
        oacc[s][dt] = __builtin_amdgcn_mfma_f32_16x16x32_bf16(pa[s][0], vb0, oacc[s][dt], 0, 0, 0);
        oacc[s][dt] = __builtin_amdgcn_mfma_f32_16x16x32_bf16(pa[s][1], vb1, oacc[s][dt], 0, 0, 0);
      }
    }
  }
  for (int s = 0; s < 2; ++s) {
    lsum[s] += __shfl_xor(lsum[s], 16);
    lsum[s] += __shfl_xor(lsum[s], 32);
  }
  if (partial) {
    float* Op = Opart + ((size_t)(bh * 13 + sidx) * 2 + half) * 4160;
    for (int s = 0; s < 2; ++s) {
      for (int dt = 0; dt < 4; ++dt)
        for (int i = 0; i < 4; ++i)
          Op[(wave * 32 + s * 16 + quad * 4 + i) * 64 + dt * 16 + l16] = oacc[s][dt][i];
      if (quad == 0) Op[4096 + wave * 32 + s * 16 + l16] = lsum[s];
    }
  } else {
    int b = bh >> 4, h = bh & 15;
    for (int s = 0; s < 2; ++s)
      for (int i = 0; i < 4; ++i) {
        float inv = 1.0f / __shfl(lsum[s], quad * 4 + i);
        int qq = q0 + wave * 32 + s * 16 + quad * 4 + i;
        size_t rowoff = ((size_t)(b * 2048 + qq)) * 1024 + h * 64;
        for (int dt = 0; dt < 4; ++dt)
          yb[rowoff + dt * 16 + l16] = f2bf(oacc[s][dt][i] * inv);
      }
  }
}

// ---- combine split halves: O = O0+O1, l = l0+l1, write normalized bf16 ----
__global__ __launch_bounds__(256) void combine_kernel(const float* __restrict__ Opart,
                                                      u16* __restrict__ yb) {
  int sidx = blockIdx.x, bh = blockIdx.y, t = threadIdx.x;
  int qtile = 31 - sidx;
  const float* A = Opart + (size_t)(bh * 13 + sidx) * 2 * 4160;
  const float* Bp = A + 4160;
  int q = t >> 2, d0 = (t & 3) << 4;
  float inv = 1.0f / (A[4096 + q] + Bp[4096 + q]);
  int b = bh >> 4, h = bh & 15;
  size_t off = ((size_t)(b * 2048 + (qtile << 6) + q)) * 1024 + h * 64 + d0;
  union { u16 hh[16]; u32x4 v[2]; } pk;
  for (int k = 0; k < 16; ++k)
    pk.hh[k] = f2bf((A[q * 64 + d0 + k] + Bp[q * 64 + d0 + k]) * inv);
  *(u32x4*)&yb[off] = pk.v[0];
  *(u32x4*)&yb[off + 8] = pk.v[1];
}

extern "C" void kernel_launch(void* const* d_in, const int* in_sizes, int n_in,
                              void* d_out, int out_size, void* d_ws, size_t ws_size,
                              hipStream_t stream) {
  const float* x     = (const float*)d_in[0];
  const float* Wkqv  = (const float*)d_in[1];
  const float* Wproj = (const float*)d_in[2];
  const float* bproj = (const float*)d_in[3];
  float* out = (float*)d_out;

  u16* ws     = (u16*)d_ws;                       // 48 MiB total scratch
  u16* xb     = ws;                               // 4096x1024 bf16 = 8.39 MB (dead after qkv)
  u16* wkqvT  = xb + (size_t)4096 * 1024;         // 3072x1024 = 6.29 MB (dead after qkv)
  u16* wprojT = wkqvT + (size_t)3072 * 1024;      // 1024x1024 (W_proj^T) -- LIVE to the end
  u16* Qh     = wprojT + (size_t)1024 * 1024;     // [32][2048][64], pre-scaled
  u16* Kh     = Qh + (size_t)32 * 2048 * 64;      // [32][2048][64]
  u16* Vt     = Kh + (size_t)32 * 2048 * 64;      // [32][64][2048] (written by qkv epilogue)
  u16* yb     = Vt + (size_t)32 * 2048 * 64;      // 4096x1024 attn out
  // Opart: 32 bh x 13 split-tiles x 2 halves x 4160 fp32 = 13.84 MB — inside dead
  // xb+wkqvT (14.68 MB); wprojT untouched.
  float* Opart = (float*)ws;

  const float QSCALE = 0.18033688011112042f;  // (1/sqrt(64)) * log2(e)

  prep_kernel<<<3072, 256, 0, stream>>>(x, Wkqv, Wproj, xb, wkqvT, wprojT);
  qkv_gemm_kernel<<<dim3(32, 24), 256, 0, stream>>>(xb, wkqvT, Qh, Kh, Vt, QSCALE);
  flash_kernel<<<1440, 128, 0, stream>>>(Qh, Kh, Vt, yb, Opart);
  combine_kernel<<<dim3(13, 32), 256, 0, stream>>>(Opart, yb);
  proj_gemm_kernel<<<dim3(32, 8), 512, 0, stream>>>(yb, wprojT, out, bproj);
}

// Round 10
// 180.284 us; speedup vs baseline: 1.1373x; 1.1373x over previous
//
#include <hip/hip_runtime.h>

// Causal MHA forward, B=2 T=2048 C=1024 H=16 hs=64, fp32 in/out, bf16 MFMA internally.
// R10: revert to measured bests — R8 flash (4-wave, XCD-grouped, swizzled; + branched
// diag mask), R8 qkv (scatter epilogue) + separate vT. Keep merged prep. proj regridded
// to 64x64 tiles x 1024 blocks (R9's (32,8) grid had 1 block/CU - nothing overlapped).

typedef unsigned short u16;
typedef unsigned int u32;
typedef __bf16 bf16x8 __attribute__((ext_vector_type(8)));
typedef float f32x4 __attribute__((ext_vector_type(4)));
typedef u32 u32x4 __attribute__((ext_vector_type(4)));
typedef u16 u16x4 __attribute__((ext_vector_type(4)));

__device__ __forceinline__ u16 f2bf(float f) {
  u32 u = __float_as_uint(f);
  u32 r = u + 0x7FFFu + ((u >> 16) & 1u);  // RNE, finite inputs only
  return (u16)(r >> 16);
}

__device__ __forceinline__ bf16x8 ld_bf8(const u16* p) {
  union { u32x4 u; bf16x8 b; } x;
  x.u = *(const u32x4*)p;
  return x.b;
}

__device__ __forceinline__ void gld_lds16(const u16* g, u16* l) {
  __builtin_amdgcn_global_load_lds(
      (const __attribute__((address_space(1))) u32*)g,
      (__attribute__((address_space(3))) u32*)l, 16, 0, 0);
}

// ---- merged prep: fp32->bf16 x-convert + both weight transpose-converts ----
__device__ __forceinline__ void convT_body(const float* __restrict__ src,
                                           u16* __restrict__ dst, int R, int Cc,
                                           int r0, int c0, float* ls /*64x65*/) {
  int t = threadIdx.x;
  for (int u = t; u < 1024; u += 256) {
    int r = u >> 4, cs = (u & 15) << 2;
    float4 v = *(const float4*)&src[(size_t)(r0 + r) * Cc + (c0 + cs)];
    ls[r * 65 + cs] = v.x; ls[r * 65 + cs + 1] = v.y;
    ls[r * 65 + cs + 2] = v.z; ls[r * 65 + cs + 3] = v.w;
  }
  __syncthreads();
  for (int u = t; u < 1024; u += 256) {
    int n = u >> 4, ks = (u & 15) << 2;
    u16x4 o;
    o.x = f2bf(ls[ks * 65 + n]); o.y = f2bf(ls[(ks + 1) * 65 + n]);
    o.z = f2bf(ls[(ks + 2) * 65 + n]); o.w = f2bf(ls[(ks + 3) * 65 + n]);
    *(u16x4*)&dst[(size_t)(c0 + n) * R + (r0 + ks)] = o;
  }
}

__global__ __launch_bounds__(256) void prep_kernel(
    const float* __restrict__ x, const float* __restrict__ Wkqv,
    const float* __restrict__ Wproj, u16* __restrict__ xb,
    u16* __restrict__ wkqvT, u16* __restrict__ wprojT) {
  __shared__ float ls[64 * 65];
  int bx = blockIdx.x;
  if (bx < 2048) {  // x -> bf16, 8 elems/thread
    int idx = bx * 256 + threadIdx.x;
    const float4* s4 = (const float4*)x;
    float4 a = s4[2 * idx], b = s4[2 * idx + 1];
    union { u16 h[8]; u32x4 v; } pk;
    pk.h[0] = f2bf(a.x); pk.h[1] = f2bf(a.y); pk.h[2] = f2bf(a.z); pk.h[3] = f2bf(a.w);
    pk.h[4] = f2bf(b.x); pk.h[5] = f2bf(b.y); pk.h[6] = f2bf(b.z); pk.h[7] = f2bf(b.w);
    *(u32x4*)&xb[(size_t)idx * 8] = pk.v;
  } else if (bx < 2816) {  // W_kqv^T (1024x3072 -> 3072x1024)
    int idx = bx - 2048;
    convT_body(Wkqv, wkqvT, 1024, 3072, (idx & 15) * 64, (idx >> 4) * 64, ls);
  } else {                 // W_proj^T (1024x1024 -> 1024x1024)
    int idx = bx - 2816;
    convT_body(Wproj, wprojT, 1024, 1024, (idx & 15) * 64, (idx >> 4) * 64, ls);
  }
}

// ---- QKV GEMM: 128x128 tile, 4 waves x (64x64), BK=32, K=1024 (R8-verified) ----
__global__ __launch_bounds__(256) void qkv_gemm_kernel(
    const u16* __restrict__ A, const u16* __restrict__ Bt,
    u16* __restrict__ Qh, u16* __restrict__ Kh, u16* __restrict__ Vh, float qscale) {
  constexpr int K = 1024;
  __shared__ __align__(16) u16 As[128 * 32];
  __shared__ __align__(16) u16 Bs[128 * 32];
  int t = threadIdx.x;
  int wave = t >> 6, lane = t & 63, quad = lane >> 4, l16 = lane & 15;
  int wm = (wave >> 1) << 6, wn = (wave & 1) << 6;
  int m0 = blockIdx.x * 128, n0 = blockIdx.y * 128;
  f32x4 acc[4][4] = {};
  int u0 = t, u1 = t + 256;
  int ra0 = u0 >> 2, ca0 = ((u0 & 3) ^ ((u0 >> 3) & 3)) << 3;
  int ra1 = u1 >> 2, ca1 = ((u1 & 3) ^ ((u1 >> 3) & 3)) << 3;
  int swq = (quad ^ ((l16 >> 1) & 3)) << 3;
  for (int k0 = 0; k0 < K; k0 += 32) {
    gld_lds16(&A[(size_t)(m0 + ra0) * K + k0 + ca0], &As[u0 * 8]);
    gld_lds16(&A[(size_t)(m0 + ra1) * K + k0 + ca1], &As[u1 * 8]);
    gld_lds16(&Bt[(size_t)(n0 + ra0) * K + k0 + ca0], &Bs[u0 * 8]);
    gld_lds16(&Bt[(size_t)(n0 + ra1) * K + k0 + ca1], &Bs[u1 * 8]);
    __syncthreads();
    bf16x8 af[4], bfr[4];
    for (int r = 0; r < 4; ++r) af[r] = ld_bf8(&As[(wm + r * 16 + l16) * 32 + swq]);
    for (int c = 0; c < 4; ++c) bfr[c] = ld_bf8(&Bs[(wn + c * 16 + l16) * 32 + swq]);
    for (int r = 0; r < 4; ++r)
      for (int c = 0; c < 4; ++c)
        acc[r][c] = __builtin_amdgcn_mfma_f32_16x16x32_bf16(af[r], bfr[c], acc[r][c], 0, 0, 0);
    __syncthreads();
  }
  for (int r = 0; r < 4; ++r) {
    int rowbase = m0 + wm + r * 16 + quad * 4;
    for (int c = 0; c < 4; ++c) {
      int col = n0 + wn + c * 16 + l16;
      int seg = col >> 10;
      int cc = col & 1023;
      int h = cc >> 6, d = cc & 63;
      for (int i = 0; i < 4; ++i) {
        int row = rowbase + i;
        int b = row >> 11, tt = row & 2047;
        size_t off = (((size_t)(b * 16 + h)) * 2048 + tt) * 64 + d;
        float v = acc[r][c][i];
        if (seg == 0)      Qh[off] = f2bf(v * qscale);
        else if (seg == 1) Kh[off] = f2bf(v);
        else               Vh[off] = f2bf(v);
      }
    }
  }
}

// ---- bf16 transpose: Vh[bh][2048][64] -> Vt[bh][64][2048] ----
__global__ __launch_bounds__(256) void vT_kernel(const u16* __restrict__ Vh,
                                                 u16* __restrict__ Vt) {
  __shared__ __align__(16) u16 ls[64 * 72];
  int t = threadIdx.x;
  int t0 = blockIdx.x * 64, bh = blockIdx.y;
  const u16* in = Vh + ((size_t)bh * 2048 + t0) * 64;
  for (int u = t; u < 512; u += 256) {
    int row = u >> 3, col = (u & 7) << 3;
    *(u32x4*)&ls[row * 72 + col] = *(const u32x4*)&in[(size_t)row * 64 + col];
  }
  __syncthreads();
  for (int u = t; u < 512; u += 256) {
    int d = u >> 3, tc = (u & 7) << 3;
    union { u16 h[8]; u32x4 v; } pk;
    for (int j = 0; j < 8; ++j) pk.h[j] = ls[(tc + j) * 72 + d];
    *(u32x4*)&Vt[((size_t)bh * 64 + d) * 2048 + t0 + tc] = pk.v;
  }
}

// ---- proj GEMM: 64x64 tile, 4 waves (2x2 grid, wave tile 32x32), grid (64,16) ----
// 1024 blocks = 4 blocks/CU = 16 waves/CU (R9's (32,8) grid left 1 block/CU idle at barriers)
__global__ __launch_bounds__(256) void proj_gemm_kernel(
    const u16* __restrict__ A, const u16* __restrict__ Bt,
    float* __restrict__ out, const float* __restrict__ bias) {
  constexpr int K = 1024;
  __shared__ __align__(16) u16 As[64 * 32];
  __shared__ __align__(16) u16 Bs[64 * 32];
  int t = threadIdx.x;
  int wave = t >> 6, lane = t & 63, quad = lane >> 4, l16 = lane & 15;
  int wm = (wave >> 1) << 5, wn = (wave & 1) << 5;
  int m0 = blockIdx.x * 64, n0 = blockIdx.y * 64;
  f32x4 acc[2][2] = {};
  int u0 = t;  // 256 units of 16B per matrix
  int ra0 = u0 >> 2, ca0 = ((u0 & 3) ^ ((u0 >> 3) & 3)) << 3;
  int swq = (quad ^ ((l16 >> 1) & 3)) << 3;
  for (int k0 = 0; k0 < K; k0 += 32) {
    gld_lds16(&A[(size_t)(m0 + ra0) * K + k0 + ca0], &As[u0 * 8]);
    gld_lds16(&Bt[(size_t)(n0 + ra0) * K + k0 + ca0], &Bs[u0 * 8]);
    __syncthreads();
    bf16x8 af[2], bfr[2];
    for (int r = 0; r < 2; ++r) af[r] = ld_bf8(&As[(wm + r * 16 + l16) * 32 + swq]);
    for (int c = 0; c < 2; ++c) bfr[c] = ld_bf8(&Bs[(wn + c * 16 + l16) * 32 + swq]);
    for (int r = 0; r < 2; ++r)
      for (int c = 0; c < 2; ++c)
        acc[r][c] = __builtin_amdgcn_mfma_f32_16x16x32_bf16(af[r], bfr[c], acc[r][c], 0, 0, 0);
    __syncthreads();
  }
  for (int r = 0; r < 2; ++r) {
    int rowbase = m0 + wm + r * 16 + quad * 4;
    for (int c = 0; c < 2; ++c) {
      int col = n0 + wn + c * 16 + l16;
      float bv = bias[col];
      for (int i = 0; i < 4; ++i)
        out[(size_t)(rowbase + i) * 1024 + col] = acc[r][c][i] + bv;
    }
  }
}

// ---- flash attention: BQ=64, 4 waves x 16 q-rows, S^T form (R8-verified structure) ----
// Rotation-swizzled stride-64 LDS; global_load_lds staging (source-permuted);
// XCD-grouped 1-D grid; branched diagonal mask (only delta vs R8).
__global__ __launch_bounds__(256, 6) void flash_kernel(
    const u16* __restrict__ Qh, const u16* __restrict__ Kh, const u16* __restrict__ Vt,
    u16* __restrict__ yb, float* __restrict__ Opart) {
  __shared__ __align__(16) u16 Ks[64 * 64];
  __shared__ __align__(16) u16 Vs[64 * 64];
  __shared__ __align__(16) u16 Ps[64 * 64];
  int t = threadIdx.x, wave = t >> 6, lane = t & 63, quad = lane >> 4, l16 = lane & 15;
  int id = blockIdx.x;                 // 0..1439
  int g = id / 360, r = id % 360;
  int bh = g * 8 + (r & 7);            // same-bh jobs share an XCD
  int jx = r >> 3;                     // 0..44, longest first
  int qtile, kvs, kve, sidx = 0, half = 0;
  bool partial;
  if (jx < 19) {                       // full jobs: qtile 18..0
    qtile = 18 - jx; kvs = 0; kve = qtile + 1; partial = false;
  } else {                             // split jobs: qtile 31..19, 2 halves (<=16 iters)
    sidx = (jx - 19) >> 1; half = (jx - 19) & 1;
    qtile = 31 - sidx;
    int nkv = qtile + 1, mid = nkv >> 1;
    kvs = half ? mid : 0; kve = half ? nkv : mid; partial = true;
  }
  int q0 = qtile << 6;
  const u16* Qb = Qh + (size_t)bh * 2048 * 64;
  const u16* Kb = Kh + (size_t)bh * 2048 * 64;
  const u16* Vb = Vt + (size_t)bh * 64 * 2048;
  bf16x8 qa0, qa1;  // B-operand frags (S^T form)
  {
    int qrow = q0 + wave * 16 + l16;
    qa0 = ld_bf8(&Qb[(size_t)qrow * 64 + quad * 8]);
    qa1 = ld_bf8(&Qb[(size_t)qrow * 64 + 32 + quad * 8]);
  }
  f32x4 oacc[4] = {};
  float lsum = 0.f;
  int u0 = wave * 128 + lane, u1 = u0 + 64;
  int r0 = u0 >> 3, p0 = u0 & 7, cb0 = (p0 - r0) & 7;
  int r1s = u1 >> 3, p1 = u1 & 7, cb1 = (p1 - r1s) & 7;
  for (int j = kvs; j < kve; ++j) {
    int kv0 = j << 6;
    __syncthreads();  // previous tile fully consumed
    gld_lds16(&Kb[(size_t)(kv0 + r0) * 64 + cb0 * 8], &Ks[u0 * 8]);
    gld_lds16(&Kb[(size_t)(kv0 + r1s) * 64 + cb1 * 8], &Ks[u1 * 8]);
    gld_lds16(&Vb[(size_t)r0 * 2048 + kv0 + cb0 * 8], &Vs[u0 * 8]);
    gld_lds16(&Vb[(size_t)r1s * 2048 + kv0 + cb1 * 8], &Vs[u1 * 8]);
    __syncthreads();  // vmcnt drain -> tiles ready
    bool maskit = (j == qtile);
    for (int c = 0; c < 4; ++c) {
      int krow = c * 16 + l16;
      bf16x8 kb0 = ld_bf8(&Ks[krow * 64 + ((quad + krow) & 7) * 8]);
      bf16x8 kb1 = ld_bf8(&Ks[krow * 64 + ((quad + 4 + krow) & 7) * 8]);
      f32x4 z = {0.f, 0.f, 0.f, 0.f};
      z = __builtin_amdgcn_mfma_f32_16x16x32_bf16(kb0, qa0, z, 0, 0, 0);
      z = __builtin_amdgcn_mfma_f32_16x16x32_bf16(kb1, qa1, z, 0, 0, 0);
      int prow = wave * 16 + l16;
      union { u16 hh[4]; u16x4 v; } pk;
      if (maskit) {
        int qg = q0 + prow;
        for (int i = 0; i < 4; ++i) {
          float p = __builtin_amdgcn_exp2f(z[i]);
          if (kv0 + c * 16 + quad * 4 + i > qg) p = 0.f;
          lsum += p;
          pk.hh[i] = f2bf(p);
        }
      } else {
        for (int i = 0; i < 4; ++i) {
          float p = __builtin_amdgcn_exp2f(z[i]);
          lsum += p;
          pk.hh[i] = f2bf(p);
        }
      }
      *(u16x4*)&Ps[prow * 64 + ((2 * c + (quad >> 1) + prow) & 7) * 8 + (quad & 1) * 4] = pk.v;
    }
    int prow = wave * 16 + l16;
    bf16x8 pa0 = ld_bf8(&Ps[prow * 64 + ((quad + prow) & 7) * 8]);      // A-frag readback
    bf16x8 pa1 = ld_bf8(&Ps[prow * 64 + ((quad + 4 + prow) & 7) * 8]);
    for (int dt = 0; dt < 4; ++dt) {
      int vrow = dt * 16 + l16;
      bf16x8 vb0 = ld_bf8(&Vs[vrow * 64 + ((quad + vrow) & 7) * 8]);
      bf16x8 vb1 = ld_bf8(&Vs[vrow * 64 + ((quad + 4 + vrow) & 7) * 8]);
      oacc[dt] = __builtin_amdgcn_mfma_f32_16x16x32_bf16(pa0, vb0, oacc[dt], 0, 0, 0);
      oacc[dt] = __builtin_amdgcn_mfma_f32_16x16x32_bf16(pa1, vb1, oacc[dt], 0, 0, 0);
    }
  }
  lsum += __shfl_xor(lsum, 16);
  lsum += __shfl_xor(lsum, 32);
  if (partial) {
    float* Op = Opart + ((size_t)(bh * 13 + sidx) * 2 + half) * 4160;
    for (int dt = 0; dt < 4; ++dt)
      for (int i = 0; i < 4; ++i)
        Op[(wave * 16 + quad * 4 + i) * 64 + dt * 16 + l16] = oacc[dt][i];
    if (quad == 0) Op[4096 + wave * 16 + l16] = lsum;
  } else {
    int b = bh >> 4, h = bh & 15;
    for (int i = 0; i < 4; ++i) {
      float inv = 1.0f / __shfl(lsum, quad * 4 + i);
      int qq = q0 + wave * 16 + quad * 4 + i;
      size_t rowoff = ((size_t)(b * 2048 + qq)) * 1024 + h * 64;
      for (int dt = 0; dt < 4; ++dt)
        yb[rowoff + dt * 16 + l16] = f2bf(oacc[dt][i] * inv);
    }
  }
}

// ---- combine split halves: O = O0+O1, l = l0+l1, write normalized bf16 ----
__global__ __launch_bounds__(256) void combine_kernel(const float* __restrict__ Opart,
                                                      u16* __restrict__ yb) {
  int sidx = blockIdx.x, bh = blockIdx.y, t = threadIdx.x;
  int qtile = 31 - sidx;
  const float* A = Opart + (size_t)(bh * 13 + sidx) * 2 * 4160;
  const float* Bp = A + 4160;
  int q = t >> 2, d0 = (t & 3) << 4;
  float inv = 1.0f / (A[4096 + q] + Bp[4096 + q]);
  int b = bh >> 4, h = bh & 15;
  size_t off = ((size_t)(b * 2048 + (qtile << 6) + q)) * 1024 + h * 64 + d0;
  union { u16 hh[16]; u32x4 v[2]; } pk;
  for (int k = 0; k < 16; ++k)
    pk.hh[k] = f2bf((A[q * 64 + d0 + k] + Bp[q * 64 + d0 + k]) * inv);
  *(u32x4*)&yb[off] = pk.v[0];
  *(u32x4*)&yb[off + 8] = pk.v[1];
}

extern "C" void kernel_launch(void* const* d_in, const int* in_sizes, int n_in,
                              void* d_out, int out_size, void* d_ws, size_t ws_size,
                              hipStream_t stream) {
  const float* x     = (const float*)d_in[0];
  const float* Wkqv  = (const float*)d_in[1];
  const float* Wproj = (const float*)d_in[2];
  const float* bproj = (const float*)d_in[3];
  float* out = (float*)d_out;

  u16* ws     = (u16*)d_ws;                       // 48 MiB total scratch
  u16* xb     = ws;                               // 4096x1024 bf16 = 8.39 MB (dead after qkv)
  u16* wkqvT  = xb + (size_t)4096 * 1024;         // 3072x1024 = 6.29 MB (dead after qkv)
  u16* wprojT = wkqvT + (size_t)3072 * 1024;      // 1024x1024 (W_proj^T) -- LIVE to the end
  u16* Qh     = wprojT + (size_t)1024 * 1024;     // [32][2048][64], pre-scaled
  u16* Kh     = Qh + (size_t)32 * 2048 * 64;      // [32][2048][64]
  u16* Vt     = Kh + (size_t)32 * 2048 * 64;      // [32][64][2048]
  u16* yb     = Vt + (size_t)32 * 2048 * 64;      // 4096x1024 attn out; doubles as Vh
  u16* Vh     = yb;
  // Opart: 32 bh x 13 split-tiles x 2 halves x 4160 fp32 = 13.84 MB — inside dead
  // xb+wkqvT (14.68 MB); wprojT untouched.
  float* Opart = (float*)ws;

  const float QSCALE = 0.18033688011112042f;  // (1/sqrt(64)) * log2(e)

  prep_kernel<<<3072, 256, 0, stream>>>(x, Wkqv, Wproj, xb, wkqvT, wprojT);
  qkv_gemm_kernel<<<dim3(32, 24), 256, 0, stream>>>(xb, wkqvT, Qh, Kh, Vh, QSCALE);
  vT_kernel<<<dim3(32, 32), 256, 0, stream>>>(Vh, Vt);
  flash_kernel<<<1440, 256, 0, stream>>>(Qh, Kh, Vt, yb, Opart);
  combine_kernel<<<dim3(13, 32), 256, 0, stream>>>(Opart, yb);
  proj_gemm_kernel<<<dim3(64, 16), 256, 0, stream>>>(yb, wprojT, out, bproj);
}